// Round 13
// baseline (111.182 us; speedup 1.0000x reference)
//
#include <hip/hip_runtime.h>
#include <hip/hip_bf16.h>

#define B_  8
#define C_  256
#define L_  4096
#define KD_ 768    // 256 ci * 3 taps, kd = ci*3 + k
#define XPW 4112   // padded x row: 8 | 4096 | 8  (bf16)

typedef __attribute__((ext_vector_type(8))) __bf16 bf16x8;
typedef __attribute__((ext_vector_type(4))) float f32x4;
typedef __attribute__((ext_vector_type(8))) unsigned short u16x8;
typedef __attribute__((ext_vector_type(2))) unsigned int u32x2;

__device__ __forceinline__ unsigned short f2bf(float f){
  union { float f; unsigned u; } v; v.f = f;
  unsigned r = v.u + 0x7fffu + ((v.u >> 16) & 1u);   // RNE
  return (unsigned short)(r >> 16);
}
__device__ __forceinline__ float bf2f(unsigned short h){
  union { unsigned u; float f; } v; v.u = ((unsigned)h) << 16;
  return v.f;
}
// pack two fp32 -> one u32 of 2x bf16 (RNE); compiles to v_cvt_pk_bf16_f32
__device__ __forceinline__ unsigned pk2bf(float lo, float hi){
  __hip_bfloat162 h2 = __float22bfloat162_rn(make_float2(lo, hi));
  unsigned u;
  __builtin_memcpy(&u, &h2, 4);
  return u;
}

// Champion swizzle: u16 index in [rows][128] u16 tile (row stride 256B).
// XOR col bits 3..6 with row bits 0..3: b128 fragment reads 2-way (free).
__device__ __forceinline__ int swz(int row, int col){
  return (row << 7) + (col ^ ((row & 15) << 3));
}

// async global->LDS: 32KB tile, 16B/lane, linear LDS dest (source pre-swizzled)
__device__ __forceinline__ void stage_tile32k(const unsigned short* __restrict__ g,
                                              unsigned short* l, int t){
  int wid = t >> 6, lane = t & 63;
  #pragma unroll
  for (int s = 0; s < 4; ++s){
    int seg = wid * 4 + s;
    const char* src = (const char*)g + seg * 1024 + lane * 16;
    char* dst = (char*)l + seg * 1024;
    __builtin_amdgcn_global_load_lds(
        (const __attribute__((address_space(1))) unsigned int*)src,
        (__attribute__((address_space(3))) unsigned int*)dst, 16, 0, 0);
  }
}

// ---- prep (fused, R9-proven): weight tiles + padded-x bf16 copy ---------------
// blocks [0,768): weights [256][768] -> bf16 swizzled tiles
//   layout [rt(2)][ch(8)][swz(row 128, col 96 pad 128)]
// blocks [768,768+2048): xpad[b][c][8 | 4096 | 8] bf16, one row per block
__global__ __launch_bounds__(256) void prep(const float* __restrict__ offw,
                                            const float* __restrict__ w,
                                            const float* __restrict__ x,
                                            unsigned short* __restrict__ wO,
                                            unsigned short* __restrict__ wM,
                                            unsigned short* __restrict__ xpad){
  int blk = blockIdx.x;
  if (blk < 768){
    int idx = blk * 256 + threadIdx.x;
    int r = idx / KD_, rem = idx % KD_;
    int rt = r >> 7, row = r & 127;
    int ch = rem / 96, col = rem % 96;
    int pos = (rt * 8 + ch) * 16384 + swz(row, col);
    wO[pos] = f2bf(offw[idx]);
    wM[pos] = f2bf(w[idx]);
  } else {
    int row = blk - 768;                       // 0..2047 (= b*256 + c)
    const float4* src = reinterpret_cast<const float4*>(x + (size_t)row * L_);
    unsigned short* dr = xpad + (size_t)row * XPW;
    int tid = threadIdx.x;
    #pragma unroll
    for (int q = 0; q < 2; ++q){
      float4 f0 = src[tid * 4 + q * 2];
      float4 f1 = src[tid * 4 + q * 2 + 1];
      u16x8 h;
      h[0]=f2bf(f0.x); h[1]=f2bf(f0.y); h[2]=f2bf(f0.z); h[3]=f2bf(f0.w);
      h[4]=f2bf(f1.x); h[5]=f2bf(f1.y); h[6]=f2bf(f1.z); h[7]=f2bf(f1.w);
      *reinterpret_cast<u16x8*>(dr + 8 + tid * 16 + q * 8) = h;
    }
    if (tid < 2){
      u16x8 z = {};
      *reinterpret_cast<u16x8*>(dr + (tid == 0 ? 0 : 8 + L_)) = z;  // pads
    }
  }
}

// ---- unified GEMM (R9 champion schedule + quad/b64/rotated Bs writes):
//   MODE 0 = off-conv (exact u16 repack from bf16 xpad), MODE 1 = deform.
//   PADDED 1 = bounds-free bf16 xpad (med3 clamp). Per chunk: issue As stage
//   (async gll) -> sample Bs (lane=l coalesced; quad units, row-rotated cols,
//   3x ds_write_b64) -> sync -> MFMA -> sync.
template <int MODE, int PADDED>
__global__ __launch_bounds__(512, 4) void dconv_gemm(
    const void* __restrict__ xsrc,
    const unsigned short* __restrict__ wT,
    const float* __restrict__ bvec,
    const unsigned short* __restrict__ off_in,
    void* __restrict__ outp){
  __shared__ __align__(16) unsigned short As[16384];   // 32KB
  __shared__ __align__(16) unsigned short Bs[16384];   // 32KB -> 2 blocks/CU

  // XCD swizzle: 512 blocks, 8 XCDs -> batch b pinned to one XCD
  int bid = blockIdx.x;
  int wk = (bid & 7) * 64 + (bid >> 3);
  int b  = wk >> 6;
  int yt = (wk >> 5) & 1;
  int lt = wk & 31;
  int l0 = lt * 128, m0 = yt * 128;

  int t = threadIdx.x, lane = t & 63, wid = t >> 6;
  int wm = wid >> 1, wn = wid & 1;               // wave tile: 32 m x 64 l
  const unsigned short* xbh = PADDED
      ? (const unsigned short*)xsrc + (size_t)b * C_ * XPW + 8
      : nullptr;
  const float* xbf = PADDED ? nullptr
      : (const float*)xsrc + (size_t)b * C_ * L_;
  const unsigned short* offp = off_in + (size_t)b * C_ * L_;
  const unsigned short* wBase = wT + (size_t)yt * 8 * 16384;
  f32x4 acc[2][4] = {};

  int lrow = t & 127;          // lanes = consecutive l: coalesced off/x loads
  int l = l0 + lrow;
  int cphase = t >> 7;         // 0..3
  int rot = (cphase + lrow) & 3;   // row-rotated quad pick: spreads write banks

  for (int ch = 0; ch < 8; ++ch){
    // async As stage issued first; drains at the barrier, hidden under sampling
    stage_tile32k(wBase + (size_t)ch * 16384, As, t);
    int cin = ch * 32;
    #pragma unroll
    for (int it = 0; it < 2; ++it){
      int q = it * 4 + rot;                    // channel quad 0..7
      int colb = q * 12;
      if (PADDED && !MODE){
        // exact im2col: pure u16 repack, no float converts
        unsigned hv[12];
        #pragma unroll
        for (int u = 0; u < 4; ++u){
          const unsigned short* xr = xbh + (size_t)(cin + q * 4 + u) * XPW + (l - 1);
          hv[u*3+0] = xr[0]; hv[u*3+1] = xr[1]; hv[u*3+2] = xr[2];
        }
        #pragma unroll
        for (int p = 0; p < 3; ++p){
          u32x2 dw;
          dw.x = hv[4*p+0] | (hv[4*p+1] << 16);
          dw.y = hv[4*p+2] | (hv[4*p+3] << 16);
          *reinterpret_cast<u32x2*>(&Bs[swz(lrow, colb + p * 4)]) = dw;
        }
      } else {
        float s[12];
        #pragma unroll
        for (int u = 0; u < 4; ++u){
          int c = cin + q * 4 + u;
          int i0; float w1;
          if (MODE){
            float off = bf2f(offp[(size_t)c * L_ + l]);
            float pos = (float)(l - 1) + off;
            if (PADDED) pos = fminf(fmaxf(pos, -6.f), (float)(L_ + 4));  // med3
            float p0 = floorf(pos);
            w1 = pos - p0; i0 = (int)p0;
          } else { i0 = l - 1; w1 = 0.f; }
          float w0 = 1.f - w1;
          if (PADDED){
            const unsigned short* xr = xbh + (size_t)c * XPW + i0;
            float v0 = bf2f(xr[0]), v1 = bf2f(xr[1]), v2 = bf2f(xr[2]), v3 = bf2f(xr[3]);
            s[u*3+0] = v0 * w0 + v1 * w1;
            s[u*3+1] = v1 * w0 + v2 * w1;
            s[u*3+2] = v2 * w0 + v3 * w1;
          } else {
            const float* xr = xbf + (size_t)c * L_;
            float v[4];
            #pragma unroll
            for (int j = 0; j < 4; ++j){
              int ix = i0 + j;
              v[j] = (MODE || j < 3) && ((unsigned)ix < (unsigned)L_) ? xr[ix] : 0.f;
            }
            #pragma unroll
            for (int k = 0; k < 3; ++k)
              s[u*3+k] = MODE ? (v[k] * w0 + v[k+1] * w1) : v[k];
          }
        }
        #pragma unroll
        for (int p = 0; p < 3; ++p){
          u32x2 dw;
          dw.x = pk2bf(s[4*p+0], s[4*p+1]);
          dw.y = pk2bf(s[4*p+2], s[4*p+3]);
          *reinterpret_cast<u32x2*>(&Bs[swz(lrow, colb + p * 4)]) = dw;
        }
      }
    }
    __syncthreads();
    // MFMA on As/Bs (cols 0..95 real, 96..127 pad never read)
    #pragma unroll
    for (int kf = 0; kf < 3; ++kf){
      int col = kf * 32 + (lane >> 4) * 8;
      bf16x8 af[2], bfv[4];
      #pragma unroll
      for (int mi = 0; mi < 2; ++mi)
        af[mi] = __builtin_bit_cast(bf16x8,
          *reinterpret_cast<const u16x8*>(&As[swz(wm * 32 + mi * 16 + (lane & 15), col)]));
      #pragma unroll
      for (int ni = 0; ni < 4; ++ni)
        bfv[ni] = __builtin_bit_cast(bf16x8,
          *reinterpret_cast<const u16x8*>(&Bs[swz(wn * 64 + ni * 16 + (lane & 15), col)]));
      #pragma unroll
      for (int mi = 0; mi < 2; ++mi)
        #pragma unroll
        for (int ni = 0; ni < 4; ++ni)
          acc[mi][ni] = __builtin_amdgcn_mfma_f32_16x16x32_bf16(af[mi], bfv[ni], acc[mi][ni], 0, 0, 0);
    }
    __syncthreads();
  }

  // ---- epilogue
  int rg = lane >> 4, cx = lane & 15;
  if (MODE == 0){
    unsigned short* ob = (unsigned short*)outp + (size_t)b * C_ * L_;
    #pragma unroll
    for (int mi = 0; mi < 2; ++mi)
      #pragma unroll
      for (int r = 0; r < 4; ++r){
        int c = m0 + wm * 32 + mi * 16 + rg * 4 + r;
        float bv = bvec[c];
        #pragma unroll
        for (int ni = 0; ni < 4; ++ni){
          int ll = l0 + wn * 64 + ni * 16 + cx;
          ob[(size_t)c * L_ + ll] = f2bf(acc[mi][ni][r] + bv);
        }
      }
  } else {
    float* ob = (float*)outp + (size_t)b * C_ * L_;
    #pragma unroll
    for (int mi = 0; mi < 2; ++mi)
      #pragma unroll
      for (int r = 0; r < 4; ++r){
        int o = m0 + wm * 32 + mi * 16 + rg * 4 + r;
        float bv = bvec[o];
        #pragma unroll
        for (int ni = 0; ni < 4; ++ni){
          int ll = l0 + wn * 64 + ni * 16 + cx;
          ob[(size_t)o * L_ + ll] = acc[mi][ni][r] + bv;
        }
      }
  }
}

extern "C" void kernel_launch(void* const* d_in, const int* in_sizes, int n_in,
                              void* d_out, int out_size, void* d_ws, size_t ws_size,
                              hipStream_t stream){
  (void)in_sizes; (void)n_in; (void)out_size;
  const float* x   = (const float*)d_in[0];
  const float* ow  = (const float*)d_in[1];
  const float* obv = (const float*)d_in[2];
  const float* w   = (const float*)d_in[3];
  const float* bv  = (const float*)d_in[4];
  float* out = (float*)d_out;

  unsigned short* wO     = (unsigned short*)d_ws;   // 2*8*16384 u16 = 512KB
  unsigned short* wM     = wO + 2 * 8 * 16384;      // 512KB
  unsigned short* off_ws = wM + 2 * 8 * 16384;      // 16MB bf16 off[b][c][l]
  unsigned short* xpad   = off_ws + (size_t)B_ * C_ * L_;   // 16.9MB bf16 padded x
  size_t need = (char*)(xpad + (size_t)B_ * C_ * XPW) - (char*)d_ws;
  bool pad_ok = ws_size >= need;

  prep<<<dim3(pad_ok ? 768 + 2048 : 768), dim3(256), 0, stream>>>(
      ow, w, x, wO, wM, xpad);
  dim3 blk(512), grd(512);
  if (pad_ok){
    dconv_gemm<0,1><<<grd, blk, 0, stream>>>(xpad, wO, obv, off_ws, off_ws);
    dconv_gemm<1,1><<<grd, blk, 0, stream>>>(xpad, wM, bv, off_ws, out);
  } else {
    dconv_gemm<0,0><<<grd, blk, 0, stream>>>(x, wO, obv, off_ws, off_ws);
    dconv_gemm<1,0><<<grd, blk, 0, stream>>>(x, wM, bv, off_ws, out);
  }
}

// Round 14
// 92.617 us; speedup vs baseline: 1.2004x; 1.2004x over previous
//
#include <hip/hip_runtime.h>
#include <hip/hip_bf16.h>

#define B_  8
#define C_  256
#define L_  4096
#define KD_ 768    // 256 ci * 3 taps, kd = ci*3 + k
#define XPW 4112   // padded x row: 8 | 4096 | 8  (bf16)

typedef __attribute__((ext_vector_type(8))) __bf16 bf16x8;
typedef __attribute__((ext_vector_type(4))) float f32x4;
typedef __attribute__((ext_vector_type(8))) unsigned short u16x8;

__device__ __forceinline__ unsigned short f2bf(float f){
  union { float f; unsigned u; } v; v.f = f;
  unsigned r = v.u + 0x7fffu + ((v.u >> 16) & 1u);   // RNE
  return (unsigned short)(r >> 16);
}
__device__ __forceinline__ float bf2f(unsigned short h){
  union { unsigned u; float f; } v; v.u = ((unsigned)h) << 16;
  return v.f;
}
// pack two fp32 -> one u32 of 2x bf16 (RNE); compiles to v_cvt_pk_bf16_f32
__device__ __forceinline__ unsigned pk2bf(float lo, float hi){
  __hip_bfloat162 h2 = __float22bfloat162_rn(make_float2(lo, hi));
  unsigned u;
  __builtin_memcpy(&u, &h2, 4);
  return u;
}

// Champion swizzle: u16 index in [rows][128] u16 tile (row stride 256B).
// XOR col bits 3..6 with row bits 0..3: b128 fragment reads 2-way (free).
__device__ __forceinline__ int swz(int row, int col){
  return (row << 7) + (col ^ ((row & 15) << 3));
}

// async global->LDS: 32KB tile, 16B/lane, linear LDS dest (source pre-swizzled)
__device__ __forceinline__ void stage_tile32k(const unsigned short* __restrict__ g,
                                              unsigned short* l, int t){
  int wid = t >> 6, lane = t & 63;
  #pragma unroll
  for (int s = 0; s < 4; ++s){
    int seg = wid * 4 + s;
    const char* src = (const char*)g + seg * 1024 + lane * 16;
    char* dst = (char*)l + seg * 1024;
    __builtin_amdgcn_global_load_lds(
        (const __attribute__((address_space(1))) unsigned int*)src,
        (__attribute__((address_space(3))) unsigned int*)dst, 16, 0, 0);
  }
}

// ---- prep: weights only (~2us) ------------------------------------------------
// [256][768] fp32 -> bf16 swizzled tiles [rt(2)][ch(8)][swz(row 128, col 96 pad 128)]
__global__ __launch_bounds__(256) void prep_w(const float* __restrict__ offw,
                                              const float* __restrict__ w,
                                              unsigned short* __restrict__ wO,
                                              unsigned short* __restrict__ wM){
  int idx = blockIdx.x * 256 + threadIdx.x;   // 768 blocks * 256 = 196608 exact
  int r = idx / KD_, rem = idx % KD_;
  int rt = r >> 7, row = r & 127;
  int ch = rem / 96, col = rem % 96;
  int pos = (rt * 8 + ch) * 16384 + swz(row, col);
  wO[pos] = f2bf(offw[idx]);
  wM[pos] = f2bf(w[idx]);
}

// ---- unified GEMM (R8/R9 champion schedule, UNTOUCHED inner loop):
//   MODE 0: offset conv, samples fp32 x directly (checked, exact). When PADDED,
//           blocks [512,2560) are DEDICATED xpad-copy blocks (0 LDS, co-resident
//           with GEMM blocks, XCD-matched to their batch) -- fused prep without
//           touching the GEMM loop.
//   MODE 1: deform conv. PADDED: bounds-free bf16 xpad gathers (med3 clamp).
template <int MODE, int PADDED>
__global__ __launch_bounds__(512, 4) void dconv_gemm(
    const float* __restrict__ x,
    unsigned short* __restrict__ xpad,
    const unsigned short* __restrict__ wT,
    const float* __restrict__ bvec,
    const unsigned short* __restrict__ off_in,
    void* __restrict__ outp){
  // ---- dedicated copy blocks (MODE0+PADDED only): one x row -> bf16 xpad row
  if (MODE == 0 && PADDED && blockIdx.x >= 512){
    int cb  = blockIdx.x - 512;              // 0..2047
    int row = (cb & 7) * 256 + (cb >> 3);    // batch = cb&7 -> matches XCD of bid&7
    const float4* src = reinterpret_cast<const float4*>(x + (size_t)row * L_);
    unsigned short* dr = xpad + (size_t)row * XPW;
    int tid = threadIdx.x;                   // 512 threads x 8 floats = 4096
    float4 f0 = src[tid * 2], f1 = src[tid * 2 + 1];
    u16x8 h;
    h[0]=f2bf(f0.x); h[1]=f2bf(f0.y); h[2]=f2bf(f0.z); h[3]=f2bf(f0.w);
    h[4]=f2bf(f1.x); h[5]=f2bf(f1.y); h[6]=f2bf(f1.z); h[7]=f2bf(f1.w);
    *reinterpret_cast<u16x8*>(dr + 8 + tid * 8) = h;
    if (tid < 2){
      u16x8 z = {};
      *reinterpret_cast<u16x8*>(dr + (tid == 0 ? 0 : 8 + L_)) = z;  // pads
    }
    return;
  }

  __shared__ __align__(16) unsigned short As[16384];   // 32KB
  __shared__ __align__(16) unsigned short Bs[16384];   // 32KB -> 2 blocks/CU

  // XCD swizzle: first 512 blocks, 8 XCDs -> batch b pinned to one XCD
  int bid = blockIdx.x;
  int wk = (bid & 7) * 64 + (bid >> 3);
  int b  = wk >> 6;
  int yt = (wk >> 5) & 1;
  int lt = wk & 31;
  int l0 = lt * 128, m0 = yt * 128;

  int t = threadIdx.x, lane = t & 63, wid = t >> 6;
  int wm = wid >> 1, wn = wid & 1;               // wave tile: 32 m x 64 l
  const float* xbf = x + (size_t)b * C_ * L_;
  const unsigned short* xbh = xpad + (size_t)b * C_ * XPW + 8;   // logical x[0]
  const unsigned short* offp = off_in + (size_t)b * C_ * L_;
  const unsigned short* wBase = wT + (size_t)yt * 8 * 16384;
  f32x4 acc[2][4] = {};

  int lrow = t & 127;          // lanes = consecutive l: coalesced off/x loads
  int l = l0 + lrow;
  int cphase = t >> 7;         // 0..3

  for (int ch = 0; ch < 8; ++ch){
    // async As stage issued first; drains at the barrier, hidden under sampling
    stage_tile32k(wBase + (size_t)ch * 16384, As, t);
    int cin = ch * 32;
    #pragma unroll
    for (int it = 0; it < 4; ++it){
      int ccp = it * 4 + cphase;                 // channel pair 0..15
      int colb = ccp * 6;
      float s[6];
      #pragma unroll
      for (int u = 0; u < 2; ++u){
        int c = cin + ccp * 2 + u;
        if (MODE == 0){
          // exact im2col from fp32 x (checked; w1=0 folds away)
          const float* xr = xbf + (size_t)c * L_;
          #pragma unroll
          for (int j = 0; j < 3; ++j){
            int ix = l - 1 + j;
            s[u*3+j] = ((unsigned)ix < (unsigned)L_) ? xr[ix] : 0.f;
          }
        } else {
          float off = bf2f(offp[(size_t)c * L_ + l]);
          float pos = (float)(l - 1) + off;
          int i0; float w1;
          if (PADDED){
            pos = fminf(fmaxf(pos, -6.f), (float)(L_ + 4));   // med3 clamp
            float p0 = floorf(pos);
            w1 = pos - p0; i0 = (int)p0;
            const unsigned short* xr = xbh + (size_t)c * XPW + i0;
            float v0 = bf2f(xr[0]), v1 = bf2f(xr[1]), v2 = bf2f(xr[2]), v3 = bf2f(xr[3]);
            float w0 = 1.f - w1;
            s[u*3+0] = v0 * w0 + v1 * w1;
            s[u*3+1] = v1 * w0 + v2 * w1;
            s[u*3+2] = v2 * w0 + v3 * w1;
          } else {
            float p0 = floorf(pos);
            w1 = pos - p0; i0 = (int)p0;
            const float* xr = xbf + (size_t)c * L_;
            float v[4]; float w0 = 1.f - w1;
            #pragma unroll
            for (int j = 0; j < 4; ++j){
              int ix = i0 + j;
              v[j] = ((unsigned)ix < (unsigned)L_) ? xr[ix] : 0.f;
            }
            #pragma unroll
            for (int k = 0; k < 3; ++k)
              s[u*3+k] = v[k] * w0 + v[k+1] * w1;
          }
        }
      }
      // 3 packed u32 writes (v_cvt_pk_bf16_f32): cols 6ccp..6ccp+5
      #pragma unroll
      for (int q = 0; q < 3; ++q)
        *reinterpret_cast<unsigned*>(&Bs[swz(lrow, colb + 2*q)]) =
            pk2bf(s[2*q], s[2*q+1]);
    }
    __syncthreads();
    // MFMA on As/Bs (cols 0..95 real, 96..127 pad never read)
    #pragma unroll
    for (int kf = 0; kf < 3; ++kf){
      int col = kf * 32 + (lane >> 4) * 8;
      bf16x8 af[2], bfv[4];
      #pragma unroll
      for (int mi = 0; mi < 2; ++mi)
        af[mi] = __builtin_bit_cast(bf16x8,
          *reinterpret_cast<const u16x8*>(&As[swz(wm * 32 + mi * 16 + (lane & 15), col)]));
      #pragma unroll
      for (int ni = 0; ni < 4; ++ni)
        bfv[ni] = __builtin_bit_cast(bf16x8,
          *reinterpret_cast<const u16x8*>(&Bs[swz(wn * 64 + ni * 16 + (lane & 15), col)]));
      #pragma unroll
      for (int mi = 0; mi < 2; ++mi)
        #pragma unroll
        for (int ni = 0; ni < 4; ++ni)
          acc[mi][ni] = __builtin_amdgcn_mfma_f32_16x16x32_bf16(af[mi], bfv[ni], acc[mi][ni], 0, 0, 0);
    }
    __syncthreads();
  }

  // ---- epilogue
  int rg = lane >> 4, cx = lane & 15;
  if (MODE == 0){
    unsigned short* ob = (unsigned short*)outp + (size_t)b * C_ * L_;
    #pragma unroll
    for (int mi = 0; mi < 2; ++mi)
      #pragma unroll
      for (int r = 0; r < 4; ++r){
        int c = m0 + wm * 32 + mi * 16 + rg * 4 + r;
        float bv = bvec[c];
        #pragma unroll
        for (int ni = 0; ni < 4; ++ni){
          int ll = l0 + wn * 64 + ni * 16 + cx;
          ob[(size_t)c * L_ + ll] = f2bf(acc[mi][ni][r] + bv);
        }
      }
  } else {
    float* ob = (float*)outp + (size_t)b * C_ * L_;
    #pragma unroll
    for (int mi = 0; mi < 2; ++mi)
      #pragma unroll
      for (int r = 0; r < 4; ++r){
        int o = m0 + wm * 32 + mi * 16 + rg * 4 + r;
        float bv = bvec[o];
        #pragma unroll
        for (int ni = 0; ni < 4; ++ni){
          int ll = l0 + wn * 64 + ni * 16 + cx;
          ob[(size_t)o * L_ + ll] = acc[mi][ni][r] + bv;
        }
      }
  }
}

extern "C" void kernel_launch(void* const* d_in, const int* in_sizes, int n_in,
                              void* d_out, int out_size, void* d_ws, size_t ws_size,
                              hipStream_t stream){
  (void)in_sizes; (void)n_in; (void)out_size;
  const float* x   = (const float*)d_in[0];
  const float* ow  = (const float*)d_in[1];
  const float* obv = (const float*)d_in[2];
  const float* w   = (const float*)d_in[3];
  const float* bv  = (const float*)d_in[4];
  float* out = (float*)d_out;

  unsigned short* wO     = (unsigned short*)d_ws;   // 2*8*16384 u16 = 512KB
  unsigned short* wM     = wO + 2 * 8 * 16384;      // 512KB
  unsigned short* off_ws = wM + 2 * 8 * 16384;      // 16MB bf16 off[b][c][l]
  unsigned short* xpad   = off_ws + (size_t)B_ * C_ * L_;   // 16.9MB bf16 padded x
  size_t need = (char*)(xpad + (size_t)B_ * C_ * XPW) - (char*)d_ws;
  bool pad_ok = ws_size >= need;

  prep_w<<<dim3(768), dim3(256), 0, stream>>>(ow, w, wO, wM);
  dim3 blk(512);
  if (pad_ok){
    dconv_gemm<0,1><<<dim3(512 + 2048), blk, 0, stream>>>(x, xpad, wO, obv, off_ws, off_ws);
    dconv_gemm<1,1><<<dim3(512),        blk, 0, stream>>>(x, xpad, wM, bv, off_ws, out);
  } else {
    dconv_gemm<0,0><<<dim3(512), blk, 0, stream>>>(x, xpad, wO, obv, off_ws, off_ws);
    dconv_gemm<1,0><<<dim3(512), blk, 0, stream>>>(x, xpad, wM, bv, off_ws, out);
  }
}

// Round 15
// 66.286 us; speedup vs baseline: 1.6773x; 1.3972x over previous
//
#include <hip/hip_runtime.h>
#include <hip/hip_bf16.h>

#define B_  8
#define C_  256
#define L_  4096
#define KD_ 768    // 256 ci * 3 taps, kd = ci*3 + k
#define XPW 4112   // padded x row: 8 | 4096 | 8  (bf16)

typedef __attribute__((ext_vector_type(8))) __bf16 bf16x8;
typedef __attribute__((ext_vector_type(4))) float f32x4;
typedef __attribute__((ext_vector_type(8))) unsigned short u16x8;
typedef __attribute__((ext_vector_type(4))) unsigned int u32x4;

__device__ __forceinline__ unsigned short f2bf(float f){
  union { float f; unsigned u; } v; v.f = f;
  unsigned r = v.u + 0x7fffu + ((v.u >> 16) & 1u);   // RNE
  return (unsigned short)(r >> 16);
}
__device__ __forceinline__ float bf2f(unsigned short h){
  union { unsigned u; float f; } v; v.u = ((unsigned)h) << 16;
  return v.f;
}
// pack two fp32 -> one u32 of 2x bf16 (RNE); compiles to v_cvt_pk_bf16_f32
__device__ __forceinline__ unsigned pk2bf(float lo, float hi){
  __hip_bfloat162 h2 = __float22bfloat162_rn(make_float2(lo, hi));
  unsigned u;
  __builtin_memcpy(&u, &h2, 4);
  return u;
}

// Champion swizzle: u16 index in [rows][128] u16 tile (row stride 256B).
// XOR col bits 3..6 with row bits 0..3: b128 reads AND b128 writes spread
// 8 16B-groups x 4 banks = all 32 banks -> ~2-way (free).
__device__ __forceinline__ int swz(int row, int col){
  return (row << 7) + (col ^ ((row & 15) << 3));
}

// async global->LDS: 32KB tile, 16B/lane, linear LDS dest (source pre-swizzled)
__device__ __forceinline__ void stage_tile32k(const unsigned short* __restrict__ g,
                                              unsigned short* l, int t){
  int wid = t >> 6, lane = t & 63;
  #pragma unroll
  for (int s = 0; s < 4; ++s){
    int seg = wid * 4 + s;
    const char* src = (const char*)g + seg * 1024 + lane * 16;
    char* dst = (char*)l + seg * 1024;
    __builtin_amdgcn_global_load_lds(
        (const __attribute__((address_space(1))) unsigned int*)src,
        (__attribute__((address_space(3))) unsigned int*)dst, 16, 0, 0);
  }
}

// ---- prep (R9-proven): weight tiles + padded-x bf16 copy ----------------------
// blocks [0,768): weights [256][768] -> bf16 swizzled tiles
//   layout [rt(2)][ch(8)][swz(row 128, col 96 pad 128)]
// blocks [768,768+2048): xpad[b][c][8 | 4096 | 8] bf16, one row per block
__global__ __launch_bounds__(256) void prep(const float* __restrict__ offw,
                                            const float* __restrict__ w,
                                            const float* __restrict__ x,
                                            unsigned short* __restrict__ wO,
                                            unsigned short* __restrict__ wM,
                                            unsigned short* __restrict__ xpad){
  int blk = blockIdx.x;
  if (blk < 768){
    int idx = blk * 256 + threadIdx.x;
    int r = idx / KD_, rem = idx % KD_;
    int rt = r >> 7, row = r & 127;
    int ch = rem / 96, col = rem % 96;
    int pos = (rt * 8 + ch) * 16384 + swz(row, col);
    wO[pos] = f2bf(offw[idx]);
    wM[pos] = f2bf(w[idx]);
  } else {
    int row = blk - 768;                       // 0..2047 (= b*256 + c)
    const float4* src = reinterpret_cast<const float4*>(x + (size_t)row * L_);
    unsigned short* dr = xpad + (size_t)row * XPW;
    int tid = threadIdx.x;
    #pragma unroll
    for (int q = 0; q < 2; ++q){
      float4 f0 = src[tid * 4 + q * 2];
      float4 f1 = src[tid * 4 + q * 2 + 1];
      u16x8 h;
      h[0]=f2bf(f0.x); h[1]=f2bf(f0.y); h[2]=f2bf(f0.z); h[3]=f2bf(f0.w);
      h[4]=f2bf(f1.x); h[5]=f2bf(f1.y); h[6]=f2bf(f1.z); h[7]=f2bf(f1.w);
      *reinterpret_cast<u16x8*>(dr + 8 + tid * 16 + q * 8) = h;
    }
    if (tid < 2){
      u16x8 z = {};
      *reinterpret_cast<u16x8*>(dr + (tid == 0 ? 0 : 8 + L_)) = z;  // pads
    }
  }
}

// ---- unified GEMM (champion schedule; Bs writes widened to b128):
//   MODE 0 = off-conv (exact u16 repack from bf16 xpad), MODE 1 = deform.
//   PADDED 1 = bounds-free bf16 xpad (med3 clamp).
// Per chunk: issue As stage (async gll) -> sample 8 channels/thread
// (lane=l coalesced, channel constant per load instr) -> 3x ds_write_b128
// -> sync -> MFMA -> sync.
template <int MODE, int PADDED>
__global__ __launch_bounds__(512, 4) void dconv_gemm(
    const void* __restrict__ xsrc,
    const unsigned short* __restrict__ wT,
    const float* __restrict__ bvec,
    const unsigned short* __restrict__ off_in,
    void* __restrict__ outp){
  __shared__ __align__(16) unsigned short As[16384];   // 32KB
  __shared__ __align__(16) unsigned short Bs[16384];   // 32KB -> 2 blocks/CU

  // XCD swizzle: 512 blocks, 8 XCDs -> batch b pinned to one XCD
  int bid = blockIdx.x;
  int wk = (bid & 7) * 64 + (bid >> 3);
  int b  = wk >> 6;
  int yt = (wk >> 5) & 1;
  int lt = wk & 31;
  int l0 = lt * 128, m0 = yt * 128;

  int t = threadIdx.x, lane = t & 63, wid = t >> 6;
  int wm = wid >> 1, wn = wid & 1;               // wave tile: 32 m x 64 l
  const unsigned short* xbh = PADDED
      ? (const unsigned short*)xsrc + (size_t)b * C_ * XPW + 8
      : nullptr;
  const float* xbf = PADDED ? nullptr
      : (const float*)xsrc + (size_t)b * C_ * L_;
  const unsigned short* offp = off_in + (size_t)b * C_ * L_;
  const unsigned short* wBase = wT + (size_t)yt * 8 * 16384;
  f32x4 acc[2][4] = {};

  int lrow = t & 127;          // lanes = consecutive l: coalesced off/x loads
  int l = l0 + lrow;
  int cphase = t >> 7;         // 0..3
  int colb = cphase * 24;      // this thread's 24-col slice (8 channels x 3 taps)

  for (int ch = 0; ch < 8; ++ch){
    // async As stage issued first; drains at the barrier, hidden under sampling
    stage_tile32k(wBase + (size_t)ch * 16384, As, t);
    int c0 = ch * 32 + cphase * 8;             // first of this thread's 8 channels
    unsigned pk[12];
    if (PADDED && !MODE){
      // exact im2col: pure u16 repack, no float converts
      unsigned hv[24];
      #pragma unroll
      for (int u = 0; u < 8; ++u){
        const unsigned short* xr = xbh + (size_t)(c0 + u) * XPW + (l - 1);
        hv[u*3+0] = xr[0]; hv[u*3+1] = xr[1]; hv[u*3+2] = xr[2];
      }
      #pragma unroll
      for (int p = 0; p < 12; ++p) pk[p] = hv[2*p] | (hv[2*p+1] << 16);
    } else {
      float s[24];
      #pragma unroll
      for (int u = 0; u < 8; ++u){
        int c = c0 + u;
        int i0; float w1;
        if (MODE){
          float off = bf2f(offp[(size_t)c * L_ + l]);
          float pos = (float)(l - 1) + off;
          if (PADDED) pos = fminf(fmaxf(pos, -6.f), (float)(L_ + 4));   // med3
          float p0 = floorf(pos);
          w1 = pos - p0; i0 = (int)p0;
        } else { i0 = l - 1; w1 = 0.f; }
        float w0 = 1.f - w1;
        if (PADDED){
          const unsigned short* xr = xbh + (size_t)c * XPW + i0;
          float v0 = bf2f(xr[0]), v1 = bf2f(xr[1]), v2 = bf2f(xr[2]), v3 = bf2f(xr[3]);
          s[u*3+0] = v0 * w0 + v1 * w1;
          s[u*3+1] = v1 * w0 + v2 * w1;
          s[u*3+2] = v2 * w0 + v3 * w1;
        } else {
          const float* xr = xbf + (size_t)c * L_;
          float v[4];
          #pragma unroll
          for (int j = 0; j < 4; ++j){
            int ix = i0 + j;
            v[j] = (MODE || j < 3) && ((unsigned)ix < (unsigned)L_) ? xr[ix] : 0.f;
          }
          #pragma unroll
          for (int k = 0; k < 3; ++k)
            s[u*3+k] = MODE ? (v[k] * w0 + v[k+1] * w1) : v[k];
        }
      }
      #pragma unroll
      for (int p = 0; p < 12; ++p) pk[p] = pk2bf(s[2*p], s[2*p+1]);
    }
    // 3x ds_write_b128: 16B-aligned (colb 8-aligned, XOR preserves it),
    // XOR spreads 8 row-groups x 4 banks = all 32 banks -> ~conflict-free
    #pragma unroll
    for (int p3 = 0; p3 < 3; ++p3){
      u32x4 dw = { pk[p3*4+0], pk[p3*4+1], pk[p3*4+2], pk[p3*4+3] };
      *reinterpret_cast<u32x4*>(&Bs[swz(lrow, colb + p3 * 8)]) = dw;
    }
    __syncthreads();
    // MFMA on As/Bs (cols 0..95 real, 96..127 pad never read)
    #pragma unroll
    for (int kf = 0; kf < 3; ++kf){
      int col = kf * 32 + (lane >> 4) * 8;
      bf16x8 af[2], bfv[4];
      #pragma unroll
      for (int mi = 0; mi < 2; ++mi)
        af[mi] = __builtin_bit_cast(bf16x8,
          *reinterpret_cast<const u16x8*>(&As[swz(wm * 32 + mi * 16 + (lane & 15), col)]));
      #pragma unroll
      for (int ni = 0; ni < 4; ++ni)
        bfv[ni] = __builtin_bit_cast(bf16x8,
          *reinterpret_cast<const u16x8*>(&Bs[swz(wn * 64 + ni * 16 + (lane & 15), col)]));
      #pragma unroll
      for (int mi = 0; mi < 2; ++mi)
        #pragma unroll
        for (int ni = 0; ni < 4; ++ni)
          acc[mi][ni] = __builtin_amdgcn_mfma_f32_16x16x32_bf16(af[mi], bfv[ni], acc[mi][ni], 0, 0, 0);
    }
    __syncthreads();
  }

  // ---- epilogue
  int rg = lane >> 4, cx = lane & 15;
  if (MODE == 0){
    unsigned short* ob = (unsigned short*)outp + (size_t)b * C_ * L_;
    #pragma unroll
    for (int mi = 0; mi < 2; ++mi)
      #pragma unroll
      for (int r = 0; r < 4; ++r){
        int c = m0 + wm * 32 + mi * 16 + rg * 4 + r;
        float bv = bvec[c];
        #pragma unroll
        for (int ni = 0; ni < 4; ++ni){
          int ll = l0 + wn * 64 + ni * 16 + cx;
          ob[(size_t)c * L_ + ll] = f2bf(acc[mi][ni][r] + bv);
        }
      }
  } else {
    float* ob = (float*)outp + (size_t)b * C_ * L_;
    #pragma unroll
    for (int mi = 0; mi < 2; ++mi)
      #pragma unroll
      for (int r = 0; r < 4; ++r){
        int o = m0 + wm * 32 + mi * 16 + rg * 4 + r;
        float bv = bvec[o];
        #pragma unroll
        for (int ni = 0; ni < 4; ++ni){
          int ll = l0 + wn * 64 + ni * 16 + cx;
          ob[(size_t)o * L_ + ll] = acc[mi][ni][r] + bv;
        }
      }
  }
}

extern "C" void kernel_launch(void* const* d_in, const int* in_sizes, int n_in,
                              void* d_out, int out_size, void* d_ws, size_t ws_size,
                              hipStream_t stream){
  (void)in_sizes; (void)n_in; (void)out_size;
  const float* x   = (const float*)d_in[0];
  const float* ow  = (const float*)d_in[1];
  const float* obv = (const float*)d_in[2];
  const float* w   = (const float*)d_in[3];
  const float* bv  = (const float*)d_in[4];
  float* out = (float*)d_out;

  unsigned short* wO     = (unsigned short*)d_ws;   // 2*8*16384 u16 = 512KB
  unsigned short* wM     = wO + 2 * 8 * 16384;      // 512KB
  unsigned short* off_ws = wM + 2 * 8 * 16384;      // 16MB bf16 off[b][c][l]
  unsigned short* xpad   = off_ws + (size_t)B_ * C_ * L_;   // 16.9MB bf16 padded x
  size_t need = (char*)(xpad + (size_t)B_ * C_ * XPW) - (char*)d_ws;
  bool pad_ok = ws_size >= need;

  prep<<<dim3(pad_ok ? 768 + 2048 : 768), dim3(256), 0, stream>>>(
      ow, w, x, wO, wM, xpad);
  dim3 blk(512), grd(512);
  if (pad_ok){
    dconv_gemm<0,1><<<grd, blk, 0, stream>>>(xpad, wO, obv, off_ws, off_ws);
    dconv_gemm<1,1><<<grd, blk, 0, stream>>>(xpad, wM, bv, off_ws, out);
  } else {
    dconv_gemm<0,0><<<grd, blk, 0, stream>>>(x, wO, obv, off_ws, off_ws);
    dconv_gemm<1,0><<<grd, blk, 0, stream>>>(x, wM, bv, off_ws, out);
  }
}